// Round 19
// baseline (445.291 us; speedup 1.0000x reference)
//
#include <hip/hip_runtime.h>
#include <math.h>

#define NROWS 16384
#define DIM   512
#define NPROTO 4096
#define TINV (1.0f / 0.9f)
#define LOSS_OFF ((size_t)NROWS * DIM)
#define IDX_OFF  ((size_t)NROWS * DIM + 1)
#define LCAP 128
#define LTHR 10.0f

typedef __attribute__((ext_vector_type(4))) int i32x4;

__global__ void zero_loss_kernel(float* out) { out[LOSS_OFF] = 0.0f; }

static __device__ __forceinline__ void gl_lds16(const void* g, void* l) {
    __builtin_amdgcn_global_load_lds((const __attribute__((address_space(1))) unsigned int*)g,
                                     (__attribute__((address_space(3))) unsigned int*)l, 16, 0, 0);
}

// ---- merged pre-split: fp32 -> 2x int8 limbs for BOTH A and P, + wsLoss zero ----
// plane layout: [g16 0..31][row][16 bytes]  (g16 covers k = g16*16 .. +16)
__global__ __launch_bounds__(256)
void split_i8_all(const float* __restrict__ A, const float* __restrict__ Pr,
                  char* __restrict__ dA1, char* __restrict__ dA0, float* __restrict__ scA,
                  char* __restrict__ dP1, char* __restrict__ dP0, float* __restrict__ scP,
                  float* __restrict__ wsLoss)
{
    __shared__ __align__(16) char s1[32][512];
    __shared__ __align__(16) char s0[32][512];
    const int tid = threadIdx.x;
    if (blockIdx.x == 0 && tid < 64) wsLoss[tid] = 0.0f;

    const bool isA = (blockIdx.x < NROWS / 32);
    const float* src = isA ? A : Pr;
    char* d1 = isA ? dA1 : dP1;
    char* d0 = isA ? dA0 : dP0;
    float* dScale = isA ? scA : scP;
    const int nrows = isA ? NROWS : NPROTO;
    const int bidx = isA ? blockIdx.x : blockIdx.x - NROWS / 32;

    const int row = tid >> 3;            // 0..31
    const int sub = tid & 7;             // 0..7 (64 elems each)
    const int r0 = bidx * 32;
    const float* rp = &src[(size_t)(r0 + row) * DIM + sub * 64];
    float v[64];
    float mx = 1e-20f;
#pragma unroll
    for (int i = 0; i < 16; ++i) {
        float4 f = *(const float4*)&rp[i * 4];
        v[i*4+0] = f.x; v[i*4+1] = f.y; v[i*4+2] = f.z; v[i*4+3] = f.w;
        mx = fmaxf(mx, fmaxf(fmaxf(fabsf(f.x), fabsf(f.y)), fmaxf(fabsf(f.z), fabsf(f.w))));
    }
#pragma unroll
    for (int off = 1; off < 8; off <<= 1) mx = fmaxf(mx, __shfl_xor(mx, off));
    const float s   = mx * (1.0f / 16256.0f);    // 16256 = 127*128
    const float inv = 16256.0f / mx;
    if (sub == 0) dScale[r0 + row] = s;
#pragma unroll
    for (int i = 0; i < 64; ++i) {
        float q  = v[i] * inv;
        float a1 = rintf(q * (1.0f / 128.0f));
        float a0 = rintf(q - 128.0f * a1);
        s1[row][sub * 64 + i] = (char)(int)a1;
        s0[row][sub * 64 + i] = (char)(int)a0;
    }
    __syncthreads();
    // write [g16][row][16]: 32 g16 x 32 rows = 1024 tiles per limb, 4 per thread
#pragma unroll
    for (int i = 0; i < 4; ++i) {
        int idx = i * 256 + tid;
        int g = idx >> 5;
        int rr = idx & 31;
        size_t o = ((size_t)g * nrows + r0 + rr) * 16;
        *(ulonglong2*)&d1[o] = *(const ulonglong2*)&s1[rr][g * 16];
        *(ulonglong2*)&d0[o] = *(const ulonglong2*)&s0[rr][g * 16];
    }
}

// ======== k1: i8 3-limb GEMM + gumbel + collect; U loads hoisted to chunk start ========
#define BM 32
#define BN 256
#define NCHUNK (NPROTO / BN)        // 16
#define NT 8                        // BK=64 -> 8 t-steps per chunk

__global__ __launch_bounds__(256, 2)
void gemm_collect2(const float* __restrict__ U,
                   int* __restrict__ gCnt, uint2* __restrict__ gList,
                   const char* __restrict__ wsA1, const char* __restrict__ wsA0,
                   const char* __restrict__ wsP1, const char* __restrict__ wsP0,
                   const float* __restrict__ wsSA, const float* __restrict__ wsSP)
{
    __shared__ __align__(16) char sA[2][2][4][BM][16];   // [buf][limb][g][row][16]   8 KB
    __shared__ __align__(16) char sP[2][2][4][BN][16];   // [buf][limb][g][proto][16] 64 KB
    __shared__ float wMax[4][BM];
    __shared__ float mRun[BM];
    __shared__ float smSA[BM];
    __shared__ int cnt[BM];

    const int tid = threadIdx.x;
    const int w = tid >> 6;
    const int lane = tid & 63;
    const int l4 = lane & 15;
    const int lh = lane >> 4;
    const int row0 = blockIdx.x * BM;

    if (tid < BM) { mRun[tid] = -1e30f; cnt[tid] = 0; smSA[tid] = wsSA[row0 + tid]; }

    // 36 stage slots (9 per wave), running-pointer form
    const char* gp[9];
    int str9[9], fx9[9], bstr9[9];
    char* ld9[9];
#pragma unroll
    for (int si = 0; si < 9; ++si) {
        int s = w * 9 + si;
        if (s < 4) {                       // A: limb=s>>1, gpair=s&1
            int limb = s >> 1, gpair = s & 1;
            int g = gpair * 2 + (lane >> 5);
            gp[si]  = (limb ? wsA0 : wsA1) + ((size_t)g * NROWS + row0 + (lane & 31)) * 16;
            str9[si] = 4 * NROWS * 16;
            fx9[si]  = -NT * 4 * NROWS * 16;            // A identical every chunk: back to t=0
            ld9[si]  = &sA[0][limb][gpair * 2][0][0] + (size_t)lane * 16;
            bstr9[si] = 2 * 4 * BM * 16;                // 4096 B
        } else {                           // P: p=s-4: limb=p>>4, g=(p&15)>>2, q=p&3
            int p = s - 4;
            int limb = p >> 4, rem = p & 15, g = rem >> 2, q = rem & 3;
            gp[si]  = (limb ? wsP0 : wsP1) + ((size_t)g * NPROTO + q * 64 + lane) * 16;
            str9[si] = 4 * NPROTO * 16;
            fx9[si]  = -NT * 4 * NPROTO * 16 + BN * 16; // next chunk's pbase, t=0
            ld9[si]  = &sP[0][limb][g][q * 64][0] + (size_t)lane * 16;
            bstr9[si] = 2 * 4 * BN * 16;                // 32768 B
        }
    }
#define DO_STAGE(b) { _Pragma("unroll") for (int si = 0; si < 9; ++si) { \
        gl_lds16(gp[si], ld9[si] + ((b) ? bstr9[si] : 0)); gp[si] += str9[si]; } }
#define DO_FIXUP() { _Pragma("unroll") for (int si = 0; si < 9; ++si) gp[si] += fx9[si]; }

    i32x4 c11[2][4], c10[2][4], c01[2][4];
    auto COMPUTE = [&](int cur) {
        i32x4 a1[2], a0[2], b1[4], b0[4];
#pragma unroll
        for (int mf = 0; mf < 2; ++mf) {
            a1[mf] = *(const i32x4*)&sA[cur][0][lh][mf * 16 + l4][0];
            a0[mf] = *(const i32x4*)&sA[cur][1][lh][mf * 16 + l4][0];
        }
#pragma unroll
        for (int nf = 0; nf < 4; ++nf) {
            b1[nf] = *(const i32x4*)&sP[cur][0][lh][w * 64 + nf * 16 + l4][0];
            b0[nf] = *(const i32x4*)&sP[cur][1][lh][w * 64 + nf * 16 + l4][0];
        }
#pragma unroll
        for (int mf = 0; mf < 2; ++mf)
#pragma unroll
            for (int nf = 0; nf < 4; ++nf) {
                c11[mf][nf] = __builtin_amdgcn_mfma_i32_16x16x64_i8(a1[mf], b1[nf], c11[mf][nf], 0, 0, 0);
                c10[mf][nf] = __builtin_amdgcn_mfma_i32_16x16x64_i8(a1[mf], b0[nf], c10[mf][nf], 0, 0, 0);
                c01[mf][nf] = __builtin_amdgcn_mfma_i32_16x16x64_i8(a0[mf], b1[nf], c01[mf][nf], 0, 0, 0);
            }
    };

    DO_STAGE(0);         // tile (chunk0, t0) -> buf0
    __syncthreads();     // drain: tile 0 ready; covers inits

    for (int ch = 0; ch < NCHUNK; ++ch) {
        const int pbase = ch * BN;
        float spv[4];
#pragma unroll
        for (int nf = 0; nf < 4; ++nf) spv[nf] = wsSP[pbase + w * 64 + nf * 16 + l4];
        // ---- hoisted U loads: issue now, consumed after the t-loop (latency hidden)
        float uu[2][4][4];
#pragma unroll
        for (int mf = 0; mf < 2; ++mf) {
            const int rb = row0 + mf * 16 + lh * 4;
#pragma unroll
            for (int nf = 0; nf < 4; ++nf)
#pragma unroll
                for (int r = 0; r < 4; ++r)
                    uu[mf][nf][r] = U[(size_t)(rb + r) * NPROTO + pbase + w * 64 + nf * 16 + l4];
        }
#pragma unroll
        for (int mf = 0; mf < 2; ++mf)
#pragma unroll
            for (int nf = 0; nf < 4; ++nf) {
                c11[mf][nf] = i32x4{0,0,0,0}; c10[mf][nf] = i32x4{0,0,0,0}; c01[mf][nf] = i32x4{0,0,0,0};
            }

#pragma unroll 2
        for (int t = 0; t < NT; ++t) {
            const int cur = t & 1;
            if (t < NT - 1) {
                DO_STAGE(cur ^ 1);
            } else if (ch + 1 < NCHUNK) {
                DO_FIXUP(); DO_STAGE(cur ^ 1);
            }
            COMPUTE(cur);
            __syncthreads();   // vmcnt(0) drain AFTER compute: next tile ready, reads of cur done
        }

        // ---- combine limbs + gumbel -> z (U already in registers)
        float zf[2][4][4];
#pragma unroll
        for (int mf = 0; mf < 2; ++mf) {
#pragma unroll
            for (int nf = 0; nf < 4; ++nf)
#pragma unroll
                for (int r = 0; r < 4; ++r) {
                    float dist = smSA[mf * 16 + lh * 4 + r] * spv[nf] *
                                 (16384.0f * (float)c11[mf][nf][r] +
                                  128.0f * ((float)c10[mf][nf][r] + (float)c01[mf][nf][r]));
                    float g = -__logf(-__logf(uu[mf][nf][r] + 1e-10f) + 1e-10f);
                    zf[mf][nf][r] = (dist + g) * TINV;
                }
        }
        // wave-slice max + inserts (threshold vs max(mRun, slice-max): conservative — mRun <= final M)
#pragma unroll
        for (int mf = 0; mf < 2; ++mf) {
            float rm[4];
#pragma unroll
            for (int r = 0; r < 4; ++r)
                rm[r] = fmaxf(fmaxf(zf[mf][0][r], zf[mf][1][r]), fmaxf(zf[mf][2][r], zf[mf][3][r]));
#pragma unroll
            for (int off = 1; off < 16; off <<= 1)
#pragma unroll
                for (int r = 0; r < 4; ++r) rm[r] = fmaxf(rm[r], __shfl_xor(rm[r], off));
#pragma unroll
            for (int r = 0; r < 4; ++r) {
                const int rl = mf * 16 + lh * 4 + r;
                float thrv = fmaxf(mRun[rl], rm[r]) - LTHR;
#pragma unroll
                for (int nf = 0; nf < 4; ++nf) {
                    float z = zf[mf][nf][r];
                    if (z > thrv) {
                        int pos = atomicAdd(&cnt[rl], 1);
                        if (pos < LCAP) {
                            uint2 en; en.x = __float_as_uint(z);
                            en.y = (unsigned)(pbase + w * 64 + nf * 16 + l4);
                            gList[(size_t)(row0 + rl) * LCAP + pos] = en;
                        }
                    }
                }
            }
            if (l4 == 0)
#pragma unroll
                for (int r = 0; r < 4; ++r) wMax[w][mf * 16 + lh * 4 + r] = rm[r];
        }
        __syncthreads();           // wMax visible; thrv readers done with mRun
        if (tid < BM) {
            float gm = fmaxf(fmaxf(wMax[0][tid], wMax[1][tid]), fmaxf(wMax[2][tid], wMax[3][tid]));
            mRun[tid] = fmaxf(mRun[tid], gm);
        }
        __syncthreads();
    }
#undef DO_STAGE
#undef DO_FIXUP

    __syncthreads();               // all LDS atomics visible
    if (tid < BM) gCnt[row0 + tid] = cnt[tid];
}

// ================= k2: per-row finish (r16-verbatim: LDS-cached list, 2-way PV) =================
__global__ __launch_bounds__(256)
void finish_kernel(const float* __restrict__ A, const float* __restrict__ Pr,
                   const float* __restrict__ U, float* __restrict__ out,
                   const int* __restrict__ gCnt, const uint2* __restrict__ gList,
                   float* __restrict__ wsLoss)
{
    __shared__ uint2 sl[4][LCAP];
    const int tid = threadIdx.x;
    const int lane = tid & 63;
    const int wv = tid >> 6;
    const int row = blockIdx.x * 4 + wv;
    const int c = min(gCnt[row], LCAP);
    const uint2* lst = &gList[(size_t)row * LCAP];

    for (int e = lane; e < c; e += 64) sl[wv][e] = lst[e];

    float M = -1e30f;
    for (int e = lane; e < c; e += 64) M = fmaxf(M, __uint_as_float(sl[wv][e].x));
#pragma unroll
    for (int off = 1; off < 64; off <<= 1) M = fmaxf(M, __shfl_xor(M, off));
    const float cutoff = M - LTHR;

    float L = 0.f, bz = -1e30f; int bi = 1 << 30;
    for (int e = lane; e < c; e += 64) {
        float z = __uint_as_float(sl[wv][e].x); int p = (int)sl[wv][e].y;
        if (z > cutoff) {
            L += __expf(z - M);
            if (z > bz || (z == bz && p < bi)) { bz = z; bi = p; }
        }
    }
#pragma unroll
    for (int off = 1; off < 64; off <<= 1) {
        L += __shfl_xor(L, off);
        float oz = __shfl_xor(bz, off); int oi = __shfl_xor(bi, off);
        if (oz > bz || (oz == bz && oi < bi)) { bz = oz; bi = oi; }
    }

    // exact argmax: r1-replica serial fp32 recompute among near-ties
    float bestz = -1e30f; int bestp = 1 << 30;
    const float* ap = &A[(size_t)row * DIM];
    for (int e = lane; e < c; e += 64) {
        float z = __uint_as_float(sl[wv][e].x);
        if (z > bz - 3.0f) {
            int p = (int)sl[wv][e].y;
            const float* pp = &Pr[(size_t)p * DIM];
            float d = 0.f;
            for (int k = 0; k < DIM; k += 4) {           // serial k order == r1's accumulation
                float4 av = *(const float4*)&ap[k];
                float4 pv = *(const float4*)&pp[k];
                d = fmaf(av.x, pv.x, d);
                d = fmaf(av.y, pv.y, d);
                d = fmaf(av.z, pv.z, d);
                d = fmaf(av.w, pv.w, d);
            }
            float u = U[(size_t)row * NPROTO + p];
            float g = -logf(-logf(u + 1e-10f) + 1e-10f); // accurate logf, as r1
            float zz = (d + g) * (1.0f / 0.9f);
            if (zz > bestz || (zz == bestz && p < bestp)) { bestz = zz; bestp = p; }
        }
    }
#pragma unroll
    for (int off = 1; off < 64; off <<= 1) {
        float oz = __shfl_xor(bestz, off); int oi = __shfl_xor(bestp, off);
        if (oz > bestz || (oz == bestz && oi < bestp)) { bestz = oz; bestp = oi; }
    }
    if (lane == 0) out[IDX_OFF + row] = (float)bestp;

    // PV gather: branchless, 2-way unrolled
    const float Li = 1.0f / L;
    float oA[8], oB[8];
#pragma unroll
    for (int q = 0; q < 8; ++q) { oA[q] = 0.f; oB[q] = 0.f; }
    for (int e = 0; e < c; e += 2) {
        const uint2 ea = sl[wv][e];
        const uint2 eb = sl[wv][(e + 1 < c) ? e + 1 : e];
        const float za = __uint_as_float(ea.x);
        const float zb = __uint_as_float(eb.x);
        const float wa = (za > cutoff) ? __expf(za - M) * Li : 0.f;
        const float wb = (e + 1 < c && zb > cutoff) ? __expf(zb - M) * Li : 0.f;
        const float* pa = &Pr[(size_t)ea.y * DIM + lane * 8];
        const float* pb = &Pr[(size_t)eb.y * DIM + lane * 8];
        float4 a0 = *(const float4*)pa;
        float4 a1 = *(const float4*)(pa + 4);
        float4 b0 = *(const float4*)pb;
        float4 b1 = *(const float4*)(pb + 4);
        oA[0] = fmaf(wa, a0.x, oA[0]); oA[1] = fmaf(wa, a0.y, oA[1]);
        oA[2] = fmaf(wa, a0.z, oA[2]); oA[3] = fmaf(wa, a0.w, oA[3]);
        oA[4] = fmaf(wa, a1.x, oA[4]); oA[5] = fmaf(wa, a1.y, oA[5]);
        oA[6] = fmaf(wa, a1.z, oA[6]); oA[7] = fmaf(wa, a1.w, oA[7]);
        oB[0] = fmaf(wb, b0.x, oB[0]); oB[1] = fmaf(wb, b0.y, oB[1]);
        oB[2] = fmaf(wb, b0.z, oB[2]); oB[3] = fmaf(wb, b0.w, oB[3]);
        oB[4] = fmaf(wb, b1.x, oB[4]); oB[5] = fmaf(wb, b1.y, oB[5]);
        oB[6] = fmaf(wb, b1.z, oB[6]); oB[7] = fmaf(wb, b1.w, oB[7]);
    }
    float o[8];
#pragma unroll
    for (int q = 0; q < 8; ++q) o[q] = oA[q] + oB[q];

    const float* fr = &A[(size_t)row * DIM + lane * 8];
    float4 f0 = *(const float4*)fr; float4 f1 = *(const float4*)(fr + 4);
    *(float4*)&out[(size_t)row * DIM + lane * 8]     = make_float4(o[0], o[1], o[2], o[3]);
    *(float4*)&out[(size_t)row * DIM + lane * 8 + 4] = make_float4(o[4], o[5], o[6], o[7]);
    float lossAcc = fabsf(o[0]-f0.x) + fabsf(o[1]-f0.y) + fabsf(o[2]-f0.z) + fabsf(o[3]-f0.w)
                  + fabsf(o[4]-f1.x) + fabsf(o[5]-f1.y) + fabsf(o[6]-f1.z) + fabsf(o[7]-f1.w);
#pragma unroll
    for (int off = 1; off < 64; off <<= 1) lossAcc += __shfl_xor(lossAcc, off);
    if (lane == 0) atomicAdd(&wsLoss[blockIdx.x & 63], lossAcc * (1.0f / ((float)NROWS * (float)DIM)));
}

__global__ void loss_final_kernel(const float* __restrict__ wsLoss, float* __restrict__ out)
{
    float s = wsLoss[threadIdx.x];
#pragma unroll
    for (int off = 1; off < 64; off <<= 1) s += __shfl_xor(s, off);
    if (threadIdx.x == 0) out[LOSS_OFF] = s;
}

// ---------------- fallback: r1 fp32 VALU kernel (no workspace needed) ----------------
#define FCAP 192
#define FTHR 20.0f

__global__ __launch_bounds__(256, 1)
void attr_proto_fused_valu(const float* __restrict__ A, const float* __restrict__ Pr,
                           const float* __restrict__ U, float* __restrict__ out)
{
    __shared__ __align__(16) float As[64][64 + 4];
    __shared__ __align__(16) float Bs[128][64 + 4];
    __shared__ float hZ[64][FCAP];
    __shared__ unsigned short hI[64][FCAP];
    __shared__ int cnt[64];
    __shared__ float mArr[64];
    __shared__ float lArr[64];
    __shared__ int pruneFlag;

    const int tid = threadIdx.x;
    const int tx = tid & 31;
    const int ty = tid >> 5;
    const int row0 = blockIdx.x * 64;

    for (int r = tid; r < 64; r += 256) cnt[r] = 0;
    if (tid == 0) pruneFlag = 0;

    float m[8], l[8], bz[8];
    int bi[8];
#pragma unroll
    for (int i = 0; i < 8; ++i) { m[i] = -INFINITY; l[i] = 0.0f; bz[i] = -INFINITY; bi[i] = 0; }
    __syncthreads();

    for (int ch = 0; ch < 32; ++ch) {
        const int pbase = ch * 128;
        float acc[8][4];
#pragma unroll
        for (int i = 0; i < 8; ++i)
#pragma unroll
            for (int j = 0; j < 4; ++j) acc[i][j] = 0.0f;

        for (int kk = 0; kk < DIM; kk += 64) {
#pragma unroll
            for (int q = 0; q < 4; ++q) {
                int lin = tid + q * 256;
                int lr = lin >> 4; int kq = (lin & 15) << 2;
                *(float4*)&As[lr][kq] = *(const float4*)&A[(size_t)(row0 + lr) * DIM + kk + kq];
            }
#pragma unroll
            for (int q = 0; q < 8; ++q) {
                int lin = tid + q * 256;
                int pr = lin >> 4; int kq = (lin & 15) << 2;
                *(float4*)&Bs[pr][kq] = *(const float4*)&Pr[(size_t)(pbase + pr) * DIM + kk + kq];
            }
            __syncthreads();
#pragma unroll 4
            for (int k4 = 0; k4 < 64; k4 += 4) {
                float4 av[8], bv[4];
#pragma unroll
                for (int i = 0; i < 8; ++i) av[i] = *(const float4*)&As[ty * 8 + i][k4];
#pragma unroll
                for (int j = 0; j < 4; ++j) bv[j] = *(const float4*)&Bs[tx + 32 * j][k4];
#pragma unroll
                for (int i = 0; i < 8; ++i)
#pragma unroll
                    for (int j = 0; j < 4; ++j) {
                        acc[i][j] += av[i].x * bv[j].x; acc[i][j] += av[i].y * bv[j].y;
                        acc[i][j] += av[i].z * bv[j].z; acc[i][j] += av[i].w * bv[j].w;
                    }
            }
            __syncthreads();
        }
#pragma unroll
        for (int i = 0; i < 8; ++i) {
            const int ri = ty * 8 + i;
            const size_t urow = (size_t)(row0 + ri) * NPROTO + pbase;
            float z[4]; float lmax = -INFINITY;
#pragma unroll
            for (int j = 0; j < 4; ++j) {
                float u = U[urow + tx + 32 * j];
                float g = -logf(-logf(u + 1e-10f) + 1e-10f);
                z[j] = (acc[i][j] + g) * TINV;
                lmax = fmaxf(lmax, z[j]);
            }
#pragma unroll
            for (int off = 16; off; off >>= 1) lmax = fmaxf(lmax, __shfl_xor(lmax, off, 32));
            const float mn = fmaxf(m[i], lmax);
            float s = 0.0f;
#pragma unroll
            for (int j = 0; j < 4; ++j) s += expf(z[j] - mn);
#pragma unroll
            for (int off = 16; off; off >>= 1) s += __shfl_xor(s, off, 32);
            l[i] = l[i] * expf(m[i] - mn) + s;
            m[i] = mn;
#pragma unroll
            for (int j = 0; j < 4; ++j) {
                const int p = pbase + tx + 32 * j;
                if (z[j] > bz[i]) { bz[i] = z[j]; bi[i] = p; }
                if (z[j] > mn - FTHR) {
                    int pos = atomicAdd(&cnt[ri], 1);
                    if (pos < FCAP) { hZ[ri][pos] = z[j]; hI[ri][pos] = (unsigned short)p; }
                }
            }
            if (tx == 0) {
                mArr[ri] = mn;
                if (cnt[ri] > 64) atomicOr(&pruneFlag, 1);
            }
        }
        __syncthreads();
        if (pruneFlag) {
            for (int r = 0; r < 64; ++r) {
                const int c0 = min(cnt[r], FCAP);
                if (c0 > 64) {
                    const float thr = mArr[r] - FTHR;
                    float ez = 0.0f; int ei = 0; bool keep = false;
                    if (tid < c0) { ez = hZ[r][tid]; ei = hI[r][tid]; keep = (ez > thr); }
                    __syncthreads();
                    if (tid == 0) cnt[r] = 0;
                    __syncthreads();
                    if (keep) { int pos = atomicAdd(&cnt[r], 1); hZ[r][pos] = ez; hI[r][pos] = (unsigned short)ei; }
                    __syncthreads();
                }
            }
            if (tid == 0) pruneFlag = 0;
            __syncthreads();
        }
    }
#pragma unroll
    for (int i = 0; i < 8; ++i) {
        const int ri = ty * 8 + i;
        float vz = bz[i]; int vi = bi[i];
#pragma unroll
        for (int off = 16; off; off >>= 1) {
            float oz = __shfl_xor(vz, off, 32); int oi = __shfl_xor(vi, off, 32);
            if (oz > vz || (oz == vz && oi < vi)) { vz = oz; vi = oi; }
        }
        if (tx == 0) { lArr[ri] = l[i]; out[IDX_OFF + row0 + ri] = (float)vi; }
    }
    __syncthreads();

    const int wv = tid >> 6;
    const int lane = tid & 63;
    float lossAcc = 0.0f;
    for (int r = wv; r < 64; r += 4) {
        const int grow = row0 + r;
        const int c = min(cnt[r], FCAP);
        const float mm = mArr[r];
        const float li = 1.0f / lArr[r];
        float o[8];
#pragma unroll
        for (int q = 0; q < 8; ++q) o[q] = 0.0f;
        for (int e = 0; e < c; ++e) {
            const float wg = expf(hZ[r][e] - mm) * li;
            const float* pp = &Pr[(size_t)hI[r][e] * DIM + lane * 8];
            float4 p0 = *(const float4*)pp; float4 p1 = *(const float4*)(pp + 4);
            o[0] += wg * p0.x; o[1] += wg * p0.y; o[2] += wg * p0.z; o[3] += wg * p0.w;
            o[4] += wg * p1.x; o[5] += wg * p1.y; o[6] += wg * p1.z; o[7] += wg * p1.w;
        }
        const float* fr = &A[(size_t)grow * DIM + lane * 8];
        float4 f0 = *(const float4*)fr; float4 f1 = *(const float4*)(fr + 4);
        *(float4*)&out[(size_t)grow * DIM + lane * 8]     = make_float4(o[0], o[1], o[2], o[3]);
        *(float4*)&out[(size_t)grow * DIM + lane * 8 + 4] = make_float4(o[4], o[5], o[6], o[7]);
        lossAcc += fabsf(o[0]-f0.x) + fabsf(o[1]-f0.y) + fabsf(o[2]-f0.z) + fabsf(o[3]-f0.w)
                 + fabsf(o[4]-f1.x) + fabsf(o[5]-f1.y) + fabsf(o[6]-f1.z) + fabsf(o[7]-f1.w);
    }
#pragma unroll
    for (int off = 32; off; off >>= 1) lossAcc += __shfl_xor(lossAcc, off, 64);
    if (lane == 0) atomicAdd(&out[LOSS_OFF], lossAcc * (1.0f / ((float)NROWS * (float)DIM)));
}

extern "C" void kernel_launch(void* const* d_in, const int* in_sizes, int n_in,
                              void* d_out, int out_size, void* d_ws, size_t ws_size,
                              hipStream_t stream)
{
    const float* A  = (const float*)d_in[0];
    const float* Pr = (const float*)d_in[1];
    const float* U  = (const float*)d_in[2];
    float* out = (float*)d_out;

    const size_t szA = (size_t)NROWS * DIM;      // bytes per A limb plane
    const size_t szP = (size_t)NPROTO * DIM;     // bytes per P limb plane
    const size_t scBytes  = (size_t)(NROWS + NPROTO) * sizeof(float);
    const size_t listBytes = (size_t)NROWS * LCAP * sizeof(uint2);
    const size_t cntBytes = (size_t)NROWS * sizeof(int);
    const size_t need = 2 * szA + 2 * szP + scBytes + listBytes + cntBytes + 64 * sizeof(float);

    if (ws_size >= need) {
        char*  wsA1 = (char*)d_ws;
        char*  wsA0 = wsA1 + szA;
        char*  wsP1 = wsA0 + szA;
        char*  wsP0 = wsP1 + szP;
        float* wsSA = (float*)(wsP0 + szP);
        float* wsSP = wsSA + NROWS;
        uint2* gList = (uint2*)(wsSP + NPROTO);
        int*   gCnt  = (int*)((char*)gList + listBytes);
        float* wsLoss = (float*)((char*)gCnt + cntBytes);
        split_i8_all<<<NROWS / 32 + NPROTO / 32, 256, 0, stream>>>(A, Pr, wsA1, wsA0, wsSA,
                                                                   wsP1, wsP0, wsSP, wsLoss);
        gemm_collect2<<<NROWS / BM, 256, 0, stream>>>(U, gCnt, gList,
                                                      wsA1, wsA0, wsP1, wsP0, wsSA, wsSP);
        finish_kernel<<<NROWS / 4, 256, 0, stream>>>(A, Pr, U, out, gCnt, gList, wsLoss);
        loss_final_kernel<<<1, 64, 0, stream>>>(wsLoss, out);
    } else {
        zero_loss_kernel<<<1, 1, 0, stream>>>(out);
        attr_proto_fused_valu<<<NROWS / 64, 256, 0, stream>>>(A, Pr, U, out);
    }
}

// Round 20
// 400.981 us; speedup vs baseline: 1.1105x; 1.1105x over previous
//
#include <hip/hip_runtime.h>
#include <math.h>

#define NROWS 16384
#define DIM   512
#define NPROTO 4096
#define TINV (1.0f / 0.9f)
#define LOSS_OFF ((size_t)NROWS * DIM)
#define IDX_OFF  ((size_t)NROWS * DIM + 1)
#define LCAP 128
#define LTHR 10.0f

typedef __attribute__((ext_vector_type(4))) int i32x4;

__global__ void zero_loss_kernel(float* out) { out[LOSS_OFF] = 0.0f; }

static __device__ __forceinline__ void gl_lds16(const void* g, void* l) {
    __builtin_amdgcn_global_load_lds((const __attribute__((address_space(1))) unsigned int*)g,
                                     (__attribute__((address_space(3))) unsigned int*)l, 16, 0, 0);
}

// ---- merged pre-split: fp32 -> 2x int8 limbs for BOTH A and P, + wsLoss zero ----
// plane layout: [g16 0..31][row][16 bytes]  (g16 covers k = g16*16 .. +16)
__global__ __launch_bounds__(256)
void split_i8_all(const float* __restrict__ A, const float* __restrict__ Pr,
                  char* __restrict__ dA1, char* __restrict__ dA0, float* __restrict__ scA,
                  char* __restrict__ dP1, char* __restrict__ dP0, float* __restrict__ scP,
                  float* __restrict__ wsLoss)
{
    __shared__ __align__(16) char s1[32][512];
    __shared__ __align__(16) char s0[32][512];
    const int tid = threadIdx.x;
    if (blockIdx.x == 0 && tid < 64) wsLoss[tid] = 0.0f;

    const bool isA = (blockIdx.x < NROWS / 32);
    const float* src = isA ? A : Pr;
    char* d1 = isA ? dA1 : dP1;
    char* d0 = isA ? dA0 : dP0;
    float* dScale = isA ? scA : scP;
    const int nrows = isA ? NROWS : NPROTO;
    const int bidx = isA ? blockIdx.x : blockIdx.x - NROWS / 32;

    const int row = tid >> 3;            // 0..31
    const int sub = tid & 7;             // 0..7 (64 elems each)
    const int r0 = bidx * 32;
    const float* rp = &src[(size_t)(r0 + row) * DIM + sub * 64];
    float v[64];
    float mx = 1e-20f;
#pragma unroll
    for (int i = 0; i < 16; ++i) {
        float4 f = *(const float4*)&rp[i * 4];
        v[i*4+0] = f.x; v[i*4+1] = f.y; v[i*4+2] = f.z; v[i*4+3] = f.w;
        mx = fmaxf(mx, fmaxf(fmaxf(fabsf(f.x), fabsf(f.y)), fmaxf(fabsf(f.z), fabsf(f.w))));
    }
#pragma unroll
    for (int off = 1; off < 8; off <<= 1) mx = fmaxf(mx, __shfl_xor(mx, off));
    const float s   = mx * (1.0f / 16256.0f);    // 16256 = 127*128
    const float inv = 16256.0f / mx;
    if (sub == 0) dScale[r0 + row] = s;
#pragma unroll
    for (int i = 0; i < 64; ++i) {
        float q  = v[i] * inv;
        float a1 = rintf(q * (1.0f / 128.0f));
        float a0 = rintf(q - 128.0f * a1);
        s1[row][sub * 64 + i] = (char)(int)a1;
        s0[row][sub * 64 + i] = (char)(int)a0;
    }
    __syncthreads();
    // write [g16][row][16]: 32 g16 x 32 rows = 1024 tiles per limb, 4 per thread
#pragma unroll
    for (int i = 0; i < 4; ++i) {
        int idx = i * 256 + tid;
        int g = idx >> 5;
        int rr = idx & 31;
        size_t o = ((size_t)g * nrows + r0 + rr) * 16;
        *(ulonglong2*)&d1[o] = *(const ulonglong2*)&s1[rr][g * 16];
        *(ulonglong2*)&d0[o] = *(const ulonglong2*)&s0[rr][g * 16];
    }
}

// ======== k1: i8 3-limb GEMM (r15/r16-verbatim) + gumbel + collect ========
#define BM 32
#define BN 256
#define NCHUNK (NPROTO / BN)        // 16
#define NT 8                        // BK=64 -> 8 t-steps per chunk

__global__ __launch_bounds__(256, 2)
void gemm_collect2(const float* __restrict__ U,
                   int* __restrict__ gCnt, uint2* __restrict__ gList,
                   const char* __restrict__ wsA1, const char* __restrict__ wsA0,
                   const char* __restrict__ wsP1, const char* __restrict__ wsP0,
                   const float* __restrict__ wsSA, const float* __restrict__ wsSP)
{
    __shared__ __align__(16) char sA[2][2][4][BM][16];   // [buf][limb][g][row][16]   8 KB
    __shared__ __align__(16) char sP[2][2][4][BN][16];   // [buf][limb][g][proto][16] 64 KB
    __shared__ float wMax[4][BM];
    __shared__ float mRun[BM];
    __shared__ float smSA[BM];
    __shared__ int cnt[BM];

    const int tid = threadIdx.x;
    const int w = tid >> 6;
    const int lane = tid & 63;
    const int l4 = lane & 15;
    const int lh = lane >> 4;
    const int row0 = blockIdx.x * BM;

    if (tid < BM) { mRun[tid] = -1e30f; cnt[tid] = 0; smSA[tid] = wsSA[row0 + tid]; }

    // 36 stage slots (9 per wave), running-pointer form
    const char* gp[9];
    int str9[9], fx9[9], bstr9[9];
    char* ld9[9];
#pragma unroll
    for (int si = 0; si < 9; ++si) {
        int s = w * 9 + si;
        if (s < 4) {                       // A: limb=s>>1, gpair=s&1
            int limb = s >> 1, gpair = s & 1;
            int g = gpair * 2 + (lane >> 5);
            gp[si]  = (limb ? wsA0 : wsA1) + ((size_t)g * NROWS + row0 + (lane & 31)) * 16;
            str9[si] = 4 * NROWS * 16;
            fx9[si]  = -NT * 4 * NROWS * 16;            // A identical every chunk: back to t=0
            ld9[si]  = &sA[0][limb][gpair * 2][0][0] + (size_t)lane * 16;
            bstr9[si] = 2 * 4 * BM * 16;                // 4096 B
        } else {                           // P: p=s-4: limb=p>>4, g=(p&15)>>2, q=p&3
            int p = s - 4;
            int limb = p >> 4, rem = p & 15, g = rem >> 2, q = rem & 3;
            gp[si]  = (limb ? wsP0 : wsP1) + ((size_t)g * NPROTO + q * 64 + lane) * 16;
            str9[si] = 4 * NPROTO * 16;
            fx9[si]  = -NT * 4 * NPROTO * 16 + BN * 16; // next chunk's pbase, t=0
            ld9[si]  = &sP[0][limb][g][q * 64][0] + (size_t)lane * 16;
            bstr9[si] = 2 * 4 * BN * 16;                // 32768 B
        }
    }
#define DO_STAGE(b) { _Pragma("unroll") for (int si = 0; si < 9; ++si) { \
        gl_lds16(gp[si], ld9[si] + ((b) ? bstr9[si] : 0)); gp[si] += str9[si]; } }
#define DO_FIXUP() { _Pragma("unroll") for (int si = 0; si < 9; ++si) gp[si] += fx9[si]; }

    i32x4 c11[2][4], c10[2][4], c01[2][4];
    auto COMPUTE = [&](int cur) {
        i32x4 a1[2], a0[2], b1[4], b0[4];
#pragma unroll
        for (int mf = 0; mf < 2; ++mf) {
            a1[mf] = *(const i32x4*)&sA[cur][0][lh][mf * 16 + l4][0];
            a0[mf] = *(const i32x4*)&sA[cur][1][lh][mf * 16 + l4][0];
        }
#pragma unroll
        for (int nf = 0; nf < 4; ++nf) {
            b1[nf] = *(const i32x4*)&sP[cur][0][lh][w * 64 + nf * 16 + l4][0];
            b0[nf] = *(const i32x4*)&sP[cur][1][lh][w * 64 + nf * 16 + l4][0];
        }
#pragma unroll
        for (int mf = 0; mf < 2; ++mf)
#pragma unroll
            for (int nf = 0; nf < 4; ++nf) {
                c11[mf][nf] = __builtin_amdgcn_mfma_i32_16x16x64_i8(a1[mf], b1[nf], c11[mf][nf], 0, 0, 0);
                c10[mf][nf] = __builtin_amdgcn_mfma_i32_16x16x64_i8(a1[mf], b0[nf], c10[mf][nf], 0, 0, 0);
                c01[mf][nf] = __builtin_amdgcn_mfma_i32_16x16x64_i8(a0[mf], b1[nf], c01[mf][nf], 0, 0, 0);
            }
    };

    DO_STAGE(0);         // tile (chunk0, t0) -> buf0
    __syncthreads();     // drain: tile 0 ready; covers inits

    for (int ch = 0; ch < NCHUNK; ++ch) {
        const int pbase = ch * BN;
        float spv[4];
#pragma unroll
        for (int nf = 0; nf < 4; ++nf) spv[nf] = wsSP[pbase + w * 64 + nf * 16 + l4];
#pragma unroll
        for (int mf = 0; mf < 2; ++mf)
#pragma unroll
            for (int nf = 0; nf < 4; ++nf) {
                c11[mf][nf] = i32x4{0,0,0,0}; c10[mf][nf] = i32x4{0,0,0,0}; c01[mf][nf] = i32x4{0,0,0,0};
            }

#pragma unroll 2
        for (int t = 0; t < NT; ++t) {
            const int cur = t & 1;
            if (t < NT - 1) {
                DO_STAGE(cur ^ 1);
            } else if (ch + 1 < NCHUNK) {
                DO_FIXUP(); DO_STAGE(cur ^ 1);
            }
            COMPUTE(cur);
            __syncthreads();   // vmcnt(0) drain AFTER compute: next tile ready, reads of cur done
        }

        // ---- combine limbs + gumbel -> z.  D layout: row=(lane>>4)*4+reg, col=lane&15
        float zf[2][4][4];
#pragma unroll
        for (int mf = 0; mf < 2; ++mf) {
            const int rb = row0 + mf * 16 + lh * 4;
#pragma unroll
            for (int nf = 0; nf < 4; ++nf)
#pragma unroll
                for (int r = 0; r < 4; ++r) {
                    float dist = smSA[mf * 16 + lh * 4 + r] * spv[nf] *
                                 (16384.0f * (float)c11[mf][nf][r] +
                                  128.0f * ((float)c10[mf][nf][r] + (float)c01[mf][nf][r]));
                    float u = U[(size_t)(rb + r) * NPROTO + pbase + w * 64 + nf * 16 + l4];
                    float g = -__logf(-__logf(u + 1e-10f) + 1e-10f);
                    zf[mf][nf][r] = (dist + g) * TINV;
                }
        }
        // wave-slice max + inserts (threshold vs max(mRun, slice-max): conservative — mRun <= final M)
#pragma unroll
        for (int mf = 0; mf < 2; ++mf) {
            float rm[4];
#pragma unroll
            for (int r = 0; r < 4; ++r)
                rm[r] = fmaxf(fmaxf(zf[mf][0][r], zf[mf][1][r]), fmaxf(zf[mf][2][r], zf[mf][3][r]));
#pragma unroll
            for (int off = 1; off < 16; off <<= 1)
#pragma unroll
                for (int r = 0; r < 4; ++r) rm[r] = fmaxf(rm[r], __shfl_xor(rm[r], off));
#pragma unroll
            for (int r = 0; r < 4; ++r) {
                const int rl = mf * 16 + lh * 4 + r;
                float thrv = fmaxf(mRun[rl], rm[r]) - LTHR;
#pragma unroll
                for (int nf = 0; nf < 4; ++nf) {
                    float z = zf[mf][nf][r];
                    if (z > thrv) {
                        int pos = atomicAdd(&cnt[rl], 1);
                        if (pos < LCAP) {
                            uint2 en; en.x = __float_as_uint(z);
                            en.y = (unsigned)(pbase + w * 64 + nf * 16 + l4);
                            gList[(size_t)(row0 + rl) * LCAP + pos] = en;
                        }
                    }
                }
            }
            if (l4 == 0)
#pragma unroll
                for (int r = 0; r < 4; ++r) wMax[w][mf * 16 + lh * 4 + r] = rm[r];
        }
        __syncthreads();           // wMax visible; thrv readers done with mRun
        if (tid < BM) {
            float gm = fmaxf(fmaxf(wMax[0][tid], wMax[1][tid]), fmaxf(wMax[2][tid], wMax[3][tid]));
            mRun[tid] = fmaxf(mRun[tid], gm);
        }
        __syncthreads();
    }
#undef DO_STAGE
#undef DO_FIXUP

    __syncthreads();               // all LDS atomics visible
    if (tid < BM) gCnt[row0 + tid] = cnt[tid];
}

// ================= k2: per-row finish (r16-verbatim: LDS-cached list, 2-way PV) =================
__global__ __launch_bounds__(256)
void finish_kernel(const float* __restrict__ A, const float* __restrict__ Pr,
                   const float* __restrict__ U, float* __restrict__ out,
                   const int* __restrict__ gCnt, const uint2* __restrict__ gList,
                   float* __restrict__ wsLoss)
{
    __shared__ uint2 sl[4][LCAP];
    const int tid = threadIdx.x;
    const int lane = tid & 63;
    const int wv = tid >> 6;
    const int row = blockIdx.x * 4 + wv;
    const int c = min(gCnt[row], LCAP);
    const uint2* lst = &gList[(size_t)row * LCAP];

    for (int e = lane; e < c; e += 64) sl[wv][e] = lst[e];

    float M = -1e30f;
    for (int e = lane; e < c; e += 64) M = fmaxf(M, __uint_as_float(sl[wv][e].x));
#pragma unroll
    for (int off = 1; off < 64; off <<= 1) M = fmaxf(M, __shfl_xor(M, off));
    const float cutoff = M - LTHR;

    float L = 0.f, bz = -1e30f; int bi = 1 << 30;
    for (int e = lane; e < c; e += 64) {
        float z = __uint_as_float(sl[wv][e].x); int p = (int)sl[wv][e].y;
        if (z > cutoff) {
            L += __expf(z - M);
            if (z > bz || (z == bz && p < bi)) { bz = z; bi = p; }
        }
    }
#pragma unroll
    for (int off = 1; off < 64; off <<= 1) {
        L += __shfl_xor(L, off);
        float oz = __shfl_xor(bz, off); int oi = __shfl_xor(bi, off);
        if (oz > bz || (oz == bz && oi < bi)) { bz = oz; bi = oi; }
    }

    // exact argmax: r1-replica serial fp32 recompute among near-ties
    float bestz = -1e30f; int bestp = 1 << 30;
    const float* ap = &A[(size_t)row * DIM];
    for (int e = lane; e < c; e += 64) {
        float z = __uint_as_float(sl[wv][e].x);
        if (z > bz - 3.0f) {
            int p = (int)sl[wv][e].y;
            const float* pp = &Pr[(size_t)p * DIM];
            float d = 0.f;
            for (int k = 0; k < DIM; k += 4) {           // serial k order == r1's accumulation
                float4 av = *(const float4*)&ap[k];
                float4 pv = *(const float4*)&pp[k];
                d = fmaf(av.x, pv.x, d);
                d = fmaf(av.y, pv.y, d);
                d = fmaf(av.z, pv.z, d);
                d = fmaf(av.w, pv.w, d);
            }
            float u = U[(size_t)row * NPROTO + p];
            float g = -logf(-logf(u + 1e-10f) + 1e-10f); // accurate logf, as r1
            float zz = (d + g) * (1.0f / 0.9f);
            if (zz > bestz || (zz == bestz && p < bestp)) { bestz = zz; bestp = p; }
        }
    }
#pragma unroll
    for (int off = 1; off < 64; off <<= 1) {
        float oz = __shfl_xor(bestz, off); int oi = __shfl_xor(bestp, off);
        if (oz > bestz || (oz == bestz && oi < bestp)) { bestz = oz; bestp = oi; }
    }
    if (lane == 0) out[IDX_OFF + row] = (float)bestp;

    // PV gather: branchless, 2-way unrolled
    const float Li = 1.0f / L;
    float oA[8], oB[8];
#pragma unroll
    for (int q = 0; q < 8; ++q) { oA[q] = 0.f; oB[q] = 0.f; }
    for (int e = 0; e < c; e += 2) {
        const uint2 ea = sl[wv][e];
        const uint2 eb = sl[wv][(e + 1 < c) ? e + 1 : e];
        const float za = __uint_as_float(ea.x);
        const float zb = __uint_as_float(eb.x);
        const float wa = (za > cutoff) ? __expf(za - M) * Li : 0.f;
        const float wb = (e + 1 < c && zb > cutoff) ? __expf(zb - M) * Li : 0.f;
        const float* pa = &Pr[(size_t)ea.y * DIM + lane * 8];
        const float* pb = &Pr[(size_t)eb.y * DIM + lane * 8];
        float4 a0 = *(const float4*)pa;
        float4 a1 = *(const float4*)(pa + 4);
        float4 b0 = *(const float4*)pb;
        float4 b1 = *(const float4*)(pb + 4);
        oA[0] = fmaf(wa, a0.x, oA[0]); oA[1] = fmaf(wa, a0.y, oA[1]);
        oA[2] = fmaf(wa, a0.z, oA[2]); oA[3] = fmaf(wa, a0.w, oA[3]);
        oA[4] = fmaf(wa, a1.x, oA[4]); oA[5] = fmaf(wa, a1.y, oA[5]);
        oA[6] = fmaf(wa, a1.z, oA[6]); oA[7] = fmaf(wa, a1.w, oA[7]);
        oB[0] = fmaf(wb, b0.x, oB[0]); oB[1] = fmaf(wb, b0.y, oB[1]);
        oB[2] = fmaf(wb, b0.z, oB[2]); oB[3] = fmaf(wb, b0.w, oB[3]);
        oB[4] = fmaf(wb, b1.x, oB[4]); oB[5] = fmaf(wb, b1.y, oB[5]);
        oB[6] = fmaf(wb, b1.z, oB[6]); oB[7] = fmaf(wb, b1.w, oB[7]);
    }
    float o[8];
#pragma unroll
    for (int q = 0; q < 8; ++q) o[q] = oA[q] + oB[q];

    const float* fr = &A[(size_t)row * DIM + lane * 8];
    float4 f0 = *(const float4*)fr; float4 f1 = *(const float4*)(fr + 4);
    *(float4*)&out[(size_t)row * DIM + lane * 8]     = make_float4(o[0], o[1], o[2], o[3]);
    *(float4*)&out[(size_t)row * DIM + lane * 8 + 4] = make_float4(o[4], o[5], o[6], o[7]);
    float lossAcc = fabsf(o[0]-f0.x) + fabsf(o[1]-f0.y) + fabsf(o[2]-f0.z) + fabsf(o[3]-f0.w)
                  + fabsf(o[4]-f1.x) + fabsf(o[5]-f1.y) + fabsf(o[6]-f1.z) + fabsf(o[7]-f1.w);
#pragma unroll
    for (int off = 1; off < 64; off <<= 1) lossAcc += __shfl_xor(lossAcc, off);
    if (lane == 0) atomicAdd(&wsLoss[blockIdx.x & 63], lossAcc * (1.0f / ((float)NROWS * (float)DIM)));
}

__global__ void loss_final_kernel(const float* __restrict__ wsLoss, float* __restrict__ out)
{
    float s = wsLoss[threadIdx.x];
#pragma unroll
    for (int off = 1; off < 64; off <<= 1) s += __shfl_xor(s, off);
    if (threadIdx.x == 0) out[LOSS_OFF] = s;
}

// ---------------- fallback: r1 fp32 VALU kernel (no workspace needed) ----------------
#define FCAP 192
#define FTHR 20.0f

__global__ __launch_bounds__(256, 1)
void attr_proto_fused_valu(const float* __restrict__ A, const float* __restrict__ Pr,
                           const float* __restrict__ U, float* __restrict__ out)
{
    __shared__ __align__(16) float As[64][64 + 4];
    __shared__ __align__(16) float Bs[128][64 + 4];
    __shared__ float hZ[64][FCAP];
    __shared__ unsigned short hI[64][FCAP];
    __shared__ int cnt[64];
    __shared__ float mArr[64];
    __shared__ float lArr[64];
    __shared__ int pruneFlag;

    const int tid = threadIdx.x;
    const int tx = tid & 31;
    const int ty = tid >> 5;
    const int row0 = blockIdx.x * 64;

    for (int r = tid; r < 64; r += 256) cnt[r] = 0;
    if (tid == 0) pruneFlag = 0;

    float m[8], l[8], bz[8];
    int bi[8];
#pragma unroll
    for (int i = 0; i < 8; ++i) { m[i] = -INFINITY; l[i] = 0.0f; bz[i] = -INFINITY; bi[i] = 0; }
    __syncthreads();

    for (int ch = 0; ch < 32; ++ch) {
        const int pbase = ch * 128;
        float acc[8][4];
#pragma unroll
        for (int i = 0; i < 8; ++i)
#pragma unroll
            for (int j = 0; j < 4; ++j) acc[i][j] = 0.0f;

        for (int kk = 0; kk < DIM; kk += 64) {
#pragma unroll
            for (int q = 0; q < 4; ++q) {
                int lin = tid + q * 256;
                int lr = lin >> 4; int kq = (lin & 15) << 2;
                *(float4*)&As[lr][kq] = *(const float4*)&A[(size_t)(row0 + lr) * DIM + kk + kq];
            }
#pragma unroll
            for (int q = 0; q < 8; ++q) {
                int lin = tid + q * 256;
                int pr = lin >> 4; int kq = (lin & 15) << 2;
                *(float4*)&Bs[pr][kq] = *(const float4*)&Pr[(size_t)(pbase + pr) * DIM + kk + kq];
            }
            __syncthreads();
#pragma unroll 4
            for (int k4 = 0; k4 < 64; k4 += 4) {
                float4 av[8], bv[4];
#pragma unroll
                for (int i = 0; i < 8; ++i) av[i] = *(const float4*)&As[ty * 8 + i][k4];
#pragma unroll
                for (int j = 0; j < 4; ++j) bv[j] = *(const float4*)&Bs[tx + 32 * j][k4];
#pragma unroll
                for (int i = 0; i < 8; ++i)
#pragma unroll
                    for (int j = 0; j < 4; ++j) {
                        acc[i][j] += av[i].x * bv[j].x; acc[i][j] += av[i].y * bv[j].y;
                        acc[i][j] += av[i].z * bv[j].z; acc[i][j] += av[i].w * bv[j].w;
                    }
            }
            __syncthreads();
        }
#pragma unroll
        for (int i = 0; i < 8; ++i) {
            const int ri = ty * 8 + i;
            const size_t urow = (size_t)(row0 + ri) * NPROTO + pbase;
            float z[4]; float lmax = -INFINITY;
#pragma unroll
            for (int j = 0; j < 4; ++j) {
                float u = U[urow + tx + 32 * j];
                float g = -logf(-logf(u + 1e-10f) + 1e-10f);
                z[j] = (acc[i][j] + g) * TINV;
                lmax = fmaxf(lmax, z[j]);
            }
#pragma unroll
            for (int off = 16; off; off >>= 1) lmax = fmaxf(lmax, __shfl_xor(lmax, off, 32));
            const float mn = fmaxf(m[i], lmax);
            float s = 0.0f;
#pragma unroll
            for (int j = 0; j < 4; ++j) s += expf(z[j] - mn);
#pragma unroll
            for (int off = 16; off; off >>= 1) s += __shfl_xor(s, off, 32);
            l[i] = l[i] * expf(m[i] - mn) + s;
            m[i] = mn;
#pragma unroll
            for (int j = 0; j < 4; ++j) {
                const int p = pbase + tx + 32 * j;
                if (z[j] > bz[i]) { bz[i] = z[j]; bi[i] = p; }
                if (z[j] > mn - FTHR) {
                    int pos = atomicAdd(&cnt[ri], 1);
                    if (pos < FCAP) { hZ[ri][pos] = z[j]; hI[ri][pos] = (unsigned short)p; }
                }
            }
            if (tx == 0) {
                mArr[ri] = mn;
                if (cnt[ri] > 64) atomicOr(&pruneFlag, 1);
            }
        }
        __syncthreads();
        if (pruneFlag) {
            for (int r = 0; r < 64; ++r) {
                const int c0 = min(cnt[r], FCAP);
                if (c0 > 64) {
                    const float thr = mArr[r] - FTHR;
                    float ez = 0.0f; int ei = 0; bool keep = false;
                    if (tid < c0) { ez = hZ[r][tid]; ei = hI[r][tid]; keep = (ez > thr); }
                    __syncthreads();
                    if (tid == 0) cnt[r] = 0;
                    __syncthreads();
                    if (keep) { int pos = atomicAdd(&cnt[r], 1); hZ[r][pos] = ez; hI[r][pos] = (unsigned short)ei; }
                    __syncthreads();
                }
            }
            if (tid == 0) pruneFlag = 0;
            __syncthreads();
        }
    }
#pragma unroll
    for (int i = 0; i < 8; ++i) {
        const int ri = ty * 8 + i;
        float vz = bz[i]; int vi = bi[i];
#pragma unroll
        for (int off = 16; off; off >>= 1) {
            float oz = __shfl_xor(vz, off, 32); int oi = __shfl_xor(vi, off, 32);
            if (oz > vz || (oz == vz && oi < vi)) { vz = oz; vi = oi; }
        }
        if (tx == 0) { lArr[ri] = l[i]; out[IDX_OFF + row0 + ri] = (float)vi; }
    }
    __syncthreads();

    const int wv = tid >> 6;
    const int lane = tid & 63;
    float lossAcc = 0.0f;
    for (int r = wv; r < 64; r += 4) {
        const int grow = row0 + r;
        const int c = min(cnt[r], FCAP);
        const float mm = mArr[r];
        const float li = 1.0f / lArr[r];
        float o[8];
#pragma unroll
        for (int q = 0; q < 8; ++q) o[q] = 0.0f;
        for (int e = 0; e < c; ++e) {
            const float wg = expf(hZ[r][e] - mm) * li;
            const float* pp = &Pr[(size_t)hI[r][e] * DIM + lane * 8];
            float4 p0 = *(const float4*)pp; float4 p1 = *(const float4*)(pp + 4);
            o[0] += wg * p0.x; o[1] += wg * p0.y; o[2] += wg * p0.z; o[3] += wg * p0.w;
            o[4] += wg * p1.x; o[5] += wg * p1.y; o[6] += wg * p1.z; o[7] += wg * p1.w;
        }
        const float* fr = &A[(size_t)grow * DIM + lane * 8];
        float4 f0 = *(const float4*)fr; float4 f1 = *(const float4*)(fr + 4);
        *(float4*)&out[(size_t)grow * DIM + lane * 8]     = make_float4(o[0], o[1], o[2], o[3]);
        *(float4*)&out[(size_t)grow * DIM + lane * 8 + 4] = make_float4(o[4], o[5], o[6], o[7]);
        lossAcc += fabsf(o[0]-f0.x) + fabsf(o[1]-f0.y) + fabsf(o[2]-f0.z) + fabsf(o[3]-f0.w)
                 + fabsf(o[4]-f1.x) + fabsf(o[5]-f1.y) + fabsf(o[6]-f1.z) + fabsf(o[7]-f1.w);
    }
#pragma unroll
    for (int off = 32; off; off >>= 1) lossAcc += __shfl_xor(lossAcc, off, 64);
    if (lane == 0) atomicAdd(&out[LOSS_OFF], lossAcc * (1.0f / ((float)NROWS * (float)DIM)));
}

extern "C" void kernel_launch(void* const* d_in, const int* in_sizes, int n_in,
                              void* d_out, int out_size, void* d_ws, size_t ws_size,
                              hipStream_t stream)
{
    const float* A  = (const float*)d_in[0];
    const float* Pr = (const float*)d_in[1];
    const float* U  = (const float*)d_in[2];
    float* out = (float*)d_out;

    const size_t szA = (size_t)NROWS * DIM;      // bytes per A limb plane
    const size_t szP = (size_t)NPROTO * DIM;     // bytes per P limb plane
    const size_t scBytes  = (size_t)(NROWS + NPROTO) * sizeof(float);
    const size_t listBytes = (size_t)NROWS * LCAP * sizeof(uint2);
    const size_t cntBytes = (size_t)NROWS * sizeof(int);
    const size_t need = 2 * szA + 2 * szP + scBytes + listBytes + cntBytes + 64 * sizeof(float);

    if (ws_size >= need) {
        char*  wsA1 = (char*)d_ws;
        char*  wsA0 = wsA1 + szA;
        char*  wsP1 = wsA0 + szA;
        char*  wsP0 = wsP1 + szP;
        float* wsSA = (float*)(wsP0 + szP);
        float* wsSP = wsSA + NROWS;
        uint2* gList = (uint2*)(wsSP + NPROTO);
        int*   gCnt  = (int*)((char*)gList + listBytes);
        float* wsLoss = (float*)((char*)gCnt + cntBytes);
        split_i8_all<<<NROWS / 32 + NPROTO / 32, 256, 0, stream>>>(A, Pr, wsA1, wsA0, wsSA,
                                                                   wsP1, wsP0, wsSP, wsLoss);
        gemm_collect2<<<NROWS / BM, 256, 0, stream>>>(U, gCnt, gList,
                                                      wsA1, wsA0, wsP1, wsP0, wsSA, wsSP);
        finish_kernel<<<NROWS / 4, 256, 0, stream>>>(A, Pr, U, out, gCnt, gList, wsLoss);
        loss_final_kernel<<<1, 64, 0, stream>>>(wsLoss, out);
    } else {
        zero_loss_kernel<<<1, 1, 0, stream>>>(out);
        attr_proto_fused_valu<<<NROWS / 64, 256, 0, stream>>>(A, Pr, U, out);
    }
}